// Round 12
// baseline (91.231 us; speedup 1.0000x reference)
//
#include <hip/hip_runtime.h>
#include <math.h>

#define BLK   256
#define BLKM  1024
#define BLKP  1024

constexpr int N_IMG = 32;
constexpr int P_PRI = 8732;
constexpr int C_CLS = 81;
constexpr int N_OBJ = 24;
constexpr int CROW  = 64;                         // rows per chunk
constexpr int CPI   = (P_PRI + CROW - 1) / CROW;  // 137 chunks per image
constexpr int NCH   = CPI * N_IMG;                // 4384 chunks
constexpr int GRIDM = 512;                        // persistent k_main blocks (2/CU)
constexpr int ROWB  = C_CLS * 4;                  // 324 B per row
constexpr int LBUF  = 21504;                      // 21 x 1024-B loads (chunk = 20736 B)

// ---------------------------------------------------------------------------
// Kernel 1: per (image, object): argmax IoU over priors (first max index).
// Also zeroes npos and the done counter.
// ---------------------------------------------------------------------------
__global__ void k_obj_match(const float* __restrict__ boxes,
                            const float* __restrict__ priors,
                            int* __restrict__ prior_for_obj,
                            int* __restrict__ npos,
                            int* __restrict__ done) {
    const int o = blockIdx.x;
    const int n = blockIdx.y;
    const int tid = threadIdx.x;

    if (o == 0 && tid == 0) npos[n] = 0;
    if (o == 0 && n == 0 && tid == 1) *done = 0;

    const float x1 = boxes[(n * N_OBJ + o) * 4 + 0];
    const float y1 = boxes[(n * N_OBJ + o) * 4 + 1];
    const float x2 = boxes[(n * N_OBJ + o) * 4 + 2];
    const float y2 = boxes[(n * N_OBJ + o) * 4 + 3];
    const float ab = (x2 - x1) * (y2 - y1);

    const float4* pr4 = (const float4*)priors;

    float bv = -1.0f;
    int   bi = P_PRI;
    for (int p = tid; p < P_PRI; p += BLK) {
        const float4 c = pr4[p];
        const float px1 = c.x - c.z / 2.0f, py1 = c.y - c.w / 2.0f;
        const float px2 = c.x + c.z / 2.0f, py2 = c.y + c.w / 2.0f;
        const float pa  = (px2 - px1) * (py2 - py1);
        const float lox = fmaxf(x1, px1), loy = fmaxf(y1, py1);
        const float hix = fminf(x2, px2), hiy = fminf(y2, py2);
        const float iw = fmaxf(hix - lox, 0.0f), ih = fmaxf(hiy - loy, 0.0f);
        const float inter = iw * ih;
        const float iou = inter / (ab + pa - inter);
        if (iou > bv) { bv = iou; bi = p; }            // ascending p keeps first max
    }

    __shared__ float sv[BLK];
    __shared__ int   si[BLK];
    sv[tid] = bv; si[tid] = bi;
    __syncthreads();
    for (int s = BLK / 2; s > 0; s >>= 1) {
        if (tid < s) {
            const float v2 = sv[tid + s]; const int i2 = si[tid + s];
            if (v2 > sv[tid] || (v2 == sv[tid] && i2 < si[tid])) { sv[tid] = v2; si[tid] = i2; }
        }
        __syncthreads();
    }
    if (tid == 0) prior_for_obj[n * N_OBJ + o] = si[0];
}

// ---------------------------------------------------------------------------
// Async DMA stage of one chunk into LDS. 1024-B per wave-instruction.
// ---------------------------------------------------------------------------
__device__ __forceinline__ void stage_chunk(const char* gb, char* lb, int nloads,
                                            int clampv, int wv, int lane) {
    for (int i = wv; i < nloads; i += BLKP / 64) {
        int off = i * 1024 + lane * 16;
        if (clampv >= 0) off = min(off, clampv);
        __builtin_amdgcn_global_load_lds(
            (const __attribute__((address_space(1))) void*)(gb + off),
            (__attribute__((address_space(3))) void*)(lb + i * 1024),
            16, 0, 0);
    }
}

// ---------------------------------------------------------------------------
// Kernel 2: persistent, double-buffered DMA-staged fused kernel.
// 512 blocks x 1024 threads (2 blocks/CU = 32 waves/CU); 64-row chunks;
// 16 lanes per row. Barrier drains hidden by the co-resident block.
// ---------------------------------------------------------------------------
__global__ void __launch_bounds__(BLKP)
k_main(const float* __restrict__ locs,
       const float* __restrict__ scores,
       const float* __restrict__ boxes,
       const int*   __restrict__ labels,
       const float* __restrict__ priors,
       const int*   __restrict__ prior_for_obj,
       float* __restrict__ conf_neg,
       int*   __restrict__ npos,
       float* __restrict__ partial_conf,
       float* __restrict__ partial_loc) {
    __shared__ char   sbuf[2][LBUF];               // 42 KB
    __shared__ float4 sbx[2][N_OBJ];
    __shared__ int    spfo[2][N_OBJ];
    __shared__ int    sslab[2][N_OBJ];
    __shared__ float  wredf[16][2];
    __shared__ int    wredi[16][2];

    const int tid  = threadIdx.x;
    const int lane = tid & 63;
    const int wv   = tid >> 6;
    const int b    = blockIdx.x;

    const int c0 = (int)(((long long)b * NCH) / GRIDM);
    const int c1 = (int)(((long long)(b + 1) * NCH) / GRIDM);   // 8-9 chunks
    const int nA = c0 / CPI;
    const int nB = (c1 - 1) / CPI;                 // spans <= 2 images

    if (tid < N_OBJ) {
        sbx [0][tid] = ((const float4*)boxes)[nA * N_OBJ + tid];
        spfo[0][tid] = prior_for_obj[nA * N_OBJ + tid];
        sslab[0][tid] = labels[nA * N_OBJ + tid];
    } else if (tid < 2 * N_OBJ) {
        const int t2 = tid - N_OBJ;
        sbx [1][t2] = ((const float4*)boxes)[nB * N_OBJ + t2];
        spfo[1][t2] = prior_for_obj[nB * N_OBJ + t2];
        sslab[1][t2] = labels[nB * N_OBJ + t2];
    }

    // prologue: stage first chunk into buf0
    {
        const int n = c0 / CPI, r0 = (c0 - n * CPI) * CROW;
        const int rows = min(CROW, P_PRI - r0);
        const char* gb = (const char*)scores + ((size_t)n * P_PRI + r0) * (size_t)ROWB;
        stage_chunk(gb, &sbuf[0][0], (rows == CROW) ? 21 : 9,
                    (c0 == NCH - 1) ? rows * ROWB - 16 : -1, wv, lane);
    }
    __syncthreads();                               // vmcnt(0) drain + meta visible

    float accC = 0.0f, accL = 0.0f;
    int   cntA = 0, cntB = 0;
    int   cur = 0;

    const int row = tid >> 4;                      // 0..63
    const int q   = tid & 15;                      // 16 lanes per row

    for (int c = c0; c < c1; ++c) {
        const int n  = c / CPI;
        const int r0 = (c - n * CPI) * CROW;
        const int rows = min(CROW, P_PRI - r0);
        const int mI = (n == nA) ? 0 : 1;

        // ---- issue DMA for next chunk into the other buffer ----
        if (c + 1 < c1) {
            const int n2 = (c + 1) / CPI, r02 = ((c + 1) - n2 * CPI) * CROW;
            const int rows2 = min(CROW, P_PRI - r02);
            const char* gb2 = (const char*)scores + ((size_t)n2 * P_PRI + r02) * (size_t)ROWB;
            stage_chunk(gb2, &sbuf[cur ^ 1][0], (rows2 == CROW) ? 21 : 9,
                        (c + 1 == NCH - 1) ? rows2 * ROWB - 16 : -1, wv, lane);
        }

        // ---- compute current chunk from LDS ----
        const float* bf = (const float*)&sbuf[cur][0];
        const bool rv = (row < rows);
        const int p = r0 + row;
        const int psafe = rv ? p : (P_PRI - 1);

        float v[5];
#pragma unroll
        for (int i = 0; i < 5; ++i) v[i] = bf[row * 81 + q + 16 * i];
        const float v80 = bf[row * 81 + 80];

        const float4 cpri = ((const float4*)priors)[psafe];
        const float px1 = cpri.x - cpri.z / 2.0f, py1 = cpri.y - cpri.w / 2.0f;
        const float px2 = cpri.x + cpri.z / 2.0f, py2 = cpri.y + cpri.w / 2.0f;
        const float pa  = (px2 - px1) * (py2 - py1);

        // match: 2 objects per lane (lanes 0..11), first-max combine over 16
        float bv = -1.0f;
        int   bo = 0;
        if (q < 12) {
#pragma unroll
            for (int j = 0; j < 2; ++j) {
                const int o = q * 2 + j;
                const float4 bb = sbx[mI][o];
                const float lox = fmaxf(bb.x, px1), loy = fmaxf(bb.y, py1);
                const float hix = fminf(bb.z, px2), hiy = fminf(bb.w, py2);
                const float iw = fmaxf(hix - lox, 0.0f), ih = fmaxf(hiy - loy, 0.0f);
                const float inter = iw * ih;
                const float ab = (bb.z - bb.x) * (bb.w - bb.y);
                const float iou = inter / (ab + pa - inter);
                if (iou > bv) { bv = iou; bo = o; }    // ascending keeps first max
            }
        }
#pragma unroll
        for (int mm = 1; mm < 16; mm <<= 1) {
            const float v2 = __shfl_xor(bv, mm);
            const int   o2 = __shfl_xor(bo, mm);
            if (v2 > bv || (v2 == bv && o2 < bo)) { bv = v2; bo = o2; }
        }

        int fo = -1;
        if (q < 12) {
#pragma unroll
            for (int j = 0; j < 2; ++j) {
                const int o = q * 2 + j;
                if (spfo[mI][o] == p) fo = o;          // ascending: last-writer-wins
            }
        }
#pragma unroll
        for (int mm = 1; mm < 16; mm <<= 1) fo = max(fo, __shfl_xor(fo, mm));

        const int   obj = (fo >= 0) ? fo : bo;
        const float ov  = (fo >= 0) ? 1.0f : bv;

        int cls = sslab[mI][obj];
        if (ov < 0.5f || !rv) cls = 0;

        // exp-sum + x[cls] selection
        float a0 = 0.0f, a1 = 0.0f, sel = 0.0f;
#pragma unroll
        for (int i = 0; i < 5; ++i) {
            const int col = q + 16 * i;
            const float e = __expf(v[i]);
            if (i & 1) a1 += e; else a0 += e;
            sel += (col == cls) ? v[i] : 0.0f;
        }
        float s = a0 + a1;
        if (q == 0) {
            s += __expf(v80);
            sel += (cls == 80) ? v80 : 0.0f;
        }
#pragma unroll
        for (int mm = 1; mm < 16; mm <<= 1) {
            s   += __shfl_xor(s, mm);
            sel += __shfl_xor(sel, mm);
        }

        int cnt1 = 0;
        if (q == 0 && rv) {
            const float conf = __logf(s) - sel;
            const bool pos = (cls != 0);
            conf_neg[n * P_PRI + p] = pos ? 0.0f : fmaxf(conf, 0.0f);
            if (pos) {
                cnt1 = 1;
                accC += conf;
                const float4 g = ((const float4*)locs)[(size_t)n * P_PRI + p];
                const float cx = g.x * cpri.z / 10.0f + cpri.x;
                const float cy = g.y * cpri.w / 10.0f + cpri.y;
                const float w  = __expf(g.z / 5.0f) * cpri.z;
                const float hh = __expf(g.w / 5.0f) * cpri.w;
                const float b1x1 = cx - w / 2.0f, b1y1 = cy - hh / 2.0f;
                const float b1x2 = cx + w / 2.0f, b1y2 = cy + hh / 2.0f;

                const float4 tb = sbx[mI][obj];
                const float w1 = b1x2 - b1x1, h1 = b1y2 - b1y1;
                const float w2 = tb.z - tb.x, h2 = tb.w - tb.y;
                const float area1 = w1 * h1,  area2 = w2 * h2;
                const float c1x = (b1x2 + b1x1) / 2.0f, c1y = (b1y2 + b1y1) / 2.0f;
                const float c2x = (tb.z + tb.x) / 2.0f, c2y = (tb.w + tb.y) / 2.0f;
                const float inw = fmaxf(fminf(b1x2, tb.z) - fmaxf(b1x1, tb.x), 0.0f);
                const float inh = fmaxf(fminf(b1y2, tb.w) - fmaxf(b1y1, tb.y), 0.0f);
                const float owd = fmaxf(fmaxf(b1x2, tb.z) - fminf(b1x1, tb.x), 0.0f);
                const float ohd = fmaxf(fmaxf(b1y2, tb.w) - fminf(b1y1, tb.y), 0.0f);
                const float inner_diag = (c2x - c1x) * (c2x - c1x) + (c2y - c1y) * (c2y - c1y);
                const float outer_diag = owd * owd + ohd * ohd;
                const float inner = inw * inh;
                const float iou = inner / (area1 + area2 - inner);
                const float K = 0.40528473456935108577551785283891f; // 4/pi^2
                const float dat = atanf(w2 / h2) - atanf(w1 / h1);
                const float vv = K * dat * dat;
                const float alpha = vv / (1.0f - iou + vv);
                accL += 1.0f - iou + inner_diag / outer_diag + alpha * vv;
            }
        }
        if (mI == 0) cntA += cnt1; else cntB += cnt1;

        cur ^= 1;
        __syncthreads();   // vmcnt(0): next-chunk DMA landed; old buf free
    }

    // ---- block-end reduction (once) ----
#pragma unroll
    for (int off = 32; off > 0; off >>= 1) {
        accC += __shfl_down(accC, off);
        accL += __shfl_down(accL, off);
        cntA += __shfl_down(cntA, off);
        cntB += __shfl_down(cntB, off);
    }
    if (lane == 0) { wredf[wv][0] = accC; wredf[wv][1] = accL;
                     wredi[wv][0] = cntA; wredi[wv][1] = cntB; }
    __syncthreads();
    if (tid == 0) {
        float C = 0.0f, L = 0.0f; int A = 0, B2 = 0;
#pragma unroll
        for (int w2 = 0; w2 < 16; ++w2) { C += wredf[w2][0]; L += wredf[w2][1];
                                          A += wredi[w2][0]; B2 += wredi[w2][1]; }
        partial_conf[b] = C;
        partial_loc [b] = L;
        atomicAdd(&npos[nA], A);
        if (nB != nA) atomicAdd(&npos[nB], B2);
    }
}

// ---------------------------------------------------------------------------
// Kernel 3: per image, exact top-k sum of conf_neg (k=3*n_pos) via 31-round
// bitwise radix-select (registers + ballot/popc). Last block also does the
// final scalar reduction.
// ---------------------------------------------------------------------------
__global__ void __launch_bounds__(BLKM)
k_mine(const float* __restrict__ conf_neg,
       const int*   __restrict__ npos,
       float* __restrict__ hardneg,
       const float* __restrict__ partial_conf,
       const float* __restrict__ partial_loc,
       int* __restrict__ done,
       float* __restrict__ out) {
    __shared__ int   wcnt[2][BLKM / 64];
    __shared__ float wsum[BLKM / 64];
    __shared__ float fs1[BLKM / 64], fs2[BLKM / 64], fs3[BLKM / 64];
    __shared__ int   fi[BLKM / 64];
    __shared__ bool  amLast;

    const int n    = blockIdx.x;
    const int tid  = threadIdx.x;
    const int wid  = tid >> 6;
    const int lane = tid & 63;

    unsigned v[9];
#pragma unroll
    for (int k = 0; k < 9; ++k) {
        const int p = tid + k * BLKM;
        v[k] = (p < P_PRI) ? __float_as_uint(conf_neg[n * P_PRI + p]) : 0u;
    }

    int k0 = 3 * npos[n];
    if (k0 > P_PRI) k0 = P_PRI;

    float result = 0.0f;
    if (k0 > 0) {
        unsigned prefix = 0u;
        int kk = k0;
        for (int bit = 30; bit >= 0; --bit) {
            const unsigned hi = (prefix >> bit) | 1u;
            int cnt = 0;
#pragma unroll
            for (int k = 0; k < 9; ++k)
                cnt += __popcll(__ballot((v[k] >> bit) == hi));
            if (lane == 0) wcnt[bit & 1][wid] = cnt;
            __syncthreads();
            int tot = 0;
#pragma unroll
            for (int w = 0; w < BLKM / 64; ++w) tot += wcnt[bit & 1][w];
            if (tot >= kk) prefix |= (1u << bit);
            else           kk -= tot;
        }

        float psum = 0.0f; int pcnt = 0;
#pragma unroll
        for (int k = 0; k < 9; ++k) {
            if (v[k] > prefix) { psum += __uint_as_float(v[k]); ++pcnt; }
        }
#pragma unroll
        for (int off = 32; off > 0; off >>= 1) {
            psum += __shfl_down(psum, off);
            pcnt += __shfl_down(pcnt, off);
        }
        __syncthreads();
        if (lane == 0) { wsum[wid] = psum; wcnt[0][wid] = pcnt; }
        __syncthreads();
        if (tid == 0) {
            float S = 0.0f; int C = 0;
#pragma unroll
            for (int w = 0; w < BLKM / 64; ++w) { S += wsum[w]; C += wcnt[0][w]; }
            result = S + (float)(k0 - C) * __uint_as_float(prefix);
        }
    }
    if (tid == 0) hardneg[n] = result;

    // ---- last block performs the final scalar reduction ----
    __threadfence();
    if (tid == 0) amLast = (atomicAdd(done, 1) == N_IMG - 1);
    __syncthreads();
    if (!amLast) return;
    __threadfence();

    float c = 0.0f, l = 0.0f, h = 0.0f;
    int np = 0;
    for (int i = tid; i < GRIDM; i += BLKM) { c += partial_conf[i]; l += partial_loc[i]; }
    if (tid < N_IMG) { h = hardneg[tid]; np = npos[tid]; }
#pragma unroll
    for (int off = 32; off > 0; off >>= 1) {
        c  += __shfl_down(c, off);
        l  += __shfl_down(l, off);
        h  += __shfl_down(h, off);
        np += __shfl_down(np, off);
    }
    if (lane == 0) { fs1[wid] = c; fs2[wid] = l; fs3[wid] = h; fi[wid] = np; }
    __syncthreads();
    if (tid == 0) {
        float C = 0.0f, L = 0.0f, H = 0.0f; int NP = 0;
#pragma unroll
        for (int w = 0; w < BLKM / 64; ++w) { C += fs1[w]; L += fs2[w]; H += fs3[w]; NP += fi[w]; }
        const float npt = (float)NP;
        out[0] = (H + C) / npt + L / npt;   // conf_loss + ALPHA * loc_loss
    }
}

// ---------------------------------------------------------------------------
extern "C" void kernel_launch(void* const* d_in, const int* in_sizes, int n_in,
                              void* d_out, int out_size, void* d_ws, size_t ws_size,
                              hipStream_t stream) {
    const float* locs   = (const float*)d_in[0];  // [N,P,4]
    const float* scores = (const float*)d_in[1];  // [N,P,C]
    const float* boxes  = (const float*)d_in[2];  // [N,NOBJ,4]
    const int*   labels = (const int*)  d_in[3];  // [N,NOBJ]
    const float* priors = (const float*)d_in[4];  // [P,4]
    float* out = (float*)d_out;

    char* w = (char*)d_ws;
    float* conf_neg      = (float*)w; w += (size_t)N_IMG * P_PRI * 4;
    int*   prior_for_obj = (int*)w;   w += (size_t)N_IMG * N_OBJ * 4;
    int*   npos          = (int*)w;   w += (size_t)N_IMG * 4;
    float* partial_conf  = (float*)w; w += (size_t)GRIDM * 4;
    float* partial_loc   = (float*)w; w += (size_t)GRIDM * 4;
    float* hardneg       = (float*)w; w += (size_t)N_IMG * 4;
    int*   done          = (int*)w;   w += 64;

    dim3 gridO(N_OBJ, N_IMG);
    k_obj_match<<<gridO, BLK, 0, stream>>>(boxes, priors, prior_for_obj, npos, done);

    k_main<<<GRIDM, BLKP, 0, stream>>>(locs, scores, boxes, labels, priors,
                                       prior_for_obj, conf_neg, npos,
                                       partial_conf, partial_loc);

    k_mine<<<N_IMG, BLKM, 0, stream>>>(conf_neg, npos, hardneg,
                                       partial_conf, partial_loc, done, out);
}